// Round 3
// baseline (28.879 us; speedup 1.0000x reference)
//
#include <hip/hip_runtime.h>

typedef __attribute__((ext_vector_type(8))) short bf16x8;
typedef __attribute__((ext_vector_type(4))) float f32x4;
typedef __attribute__((ext_vector_type(2))) float f32x2;

__device__ __forceinline__ short f2bf(float x) {
    union { float f; unsigned u; } v; v.f = x;
    unsigned r = v.u + 0x7FFFu + ((v.u >> 16) & 1u);   // round-to-nearest-even bf16
    return (short)(r >> 16);
}

// Fused skinny GEMMs, K split 4-ways across blocks for occupancy.
//   grid.x = 2048: tile = bid>>2 (0..511), kchunk = bid&3 (K slice of 256)
//   tiles 0..255  : seqE[m][r] = sum_k hs[m*1024+k]          * seqW[r][k]  (m=b*S+s, k=h)
//   tiles 256..511: hidE[m][r] = sum_k hs[b*2^20+k*1024+h]   * hidW[r][k]  (m=b*H+h, k=s)
// 4 waves/block, wave wv owns k in [kchunk*256+wv*64, +64) (2 MFMA k-steps);
// LDS reduce across waves -> chunk partial P[kchunk][half][m][r].
// MFMA k-slot mapping kg(g,j)=8g+j used identically for A and B fragments ->
// result invariant to the HW's internal k permutation.
__global__ __launch_bounds__(256) void gemm_fused(
    const float* __restrict__ hs, const float* __restrict__ seqW,
    const float* __restrict__ hidW, float* __restrict__ P /* [4][2][4096][32] */)
{
    __shared__ float red[4][16][32];

    const int bid   = blockIdx.x;
    const int tile  = bid >> 2;
    const int kchunk = bid & 3;
    const bool hid  = tile >= 256;
    const int mt    = hid ? tile - 256 : tile;
    const int tid = threadIdx.x;
    const int wv  = tid >> 6;
    const int l   = tid & 63;
    const int l15 = l & 15;
    const int g   = l >> 4;
    const int m0  = mt * 16;
    const int mrow = m0 + l15;

    const float* __restrict__ W = hid ? hidW : seqW;
    size_t arow;
    if (hid) arow = ((size_t)(mrow >> 10) << 20) + (size_t)(mrow & 1023);
    else     arow = (size_t)mrow << 10;

    f32x4 acc0 = {0.f,0.f,0.f,0.f}, acc1 = {0.f,0.f,0.f,0.f};
    const int kbase = kchunk * 256 + wv * 64;

    #pragma unroll
    for (int ks = 0; ks < 2; ++ks) {
        const int kb = kbase + ks * 32 + g * 8;
        bf16x8 af, bf0, bf1;
        if (hid) {
            const float* pa = hs + arow + (size_t)kb * 1024;
            #pragma unroll
            for (int j = 0; j < 8; ++j) af[j] = f2bf(pa[(size_t)j * 1024]);
        } else {
            const f32x4* pa = (const f32x4*)(hs + arow + kb);
            f32x4 a0 = pa[0], a1 = pa[1];
            af[0]=f2bf(a0.x); af[1]=f2bf(a0.y); af[2]=f2bf(a0.z); af[3]=f2bf(a0.w);
            af[4]=f2bf(a1.x); af[5]=f2bf(a1.y); af[6]=f2bf(a1.z); af[7]=f2bf(a1.w);
        }
        {
            const f32x4* pb = (const f32x4*)(W + (size_t)l15 * 1024 + kb);
            f32x4 b0 = pb[0], b1 = pb[1];
            bf0[0]=f2bf(b0.x); bf0[1]=f2bf(b0.y); bf0[2]=f2bf(b0.z); bf0[3]=f2bf(b0.w);
            bf0[4]=f2bf(b1.x); bf0[5]=f2bf(b1.y); bf0[6]=f2bf(b1.z); bf0[7]=f2bf(b1.w);
        }
        {
            const f32x4* pb = (const f32x4*)(W + (size_t)(l15 + 16) * 1024 + kb);
            f32x4 b0 = pb[0], b1 = pb[1];
            bf1[0]=f2bf(b0.x); bf1[1]=f2bf(b0.y); bf1[2]=f2bf(b0.z); bf1[3]=f2bf(b0.w);
            bf1[4]=f2bf(b1.x); bf1[5]=f2bf(b1.y); bf1[6]=f2bf(b1.z); bf1[7]=f2bf(b1.w);
        }
        acc0 = __builtin_amdgcn_mfma_f32_16x16x32_bf16(af, bf0, acc0, 0, 0, 0);
        acc1 = __builtin_amdgcn_mfma_f32_16x16x32_bf16(af, bf1, acc1, 0, 0, 0);
    }

    // C/D layout (m89-verified): col = lane&15, row = (lane>>4)*4 + reg
    #pragma unroll
    for (int r = 0; r < 4; ++r) {
        red[wv][4 * g + r][l15]      = acc0[r];
        red[wv][4 * g + r][l15 + 16] = acc1[r];
    }
    __syncthreads();

    // Sum 4 wave-partials; each thread writes 2 consecutive floats.
    const int o = tid * 2;
    const float* rf = &red[0][0][0];
    f32x2 v;
    v.x = rf[o]     + rf[512 + o]     + rf[1024 + o]     + rf[1536 + o];
    v.y = rf[o + 1] + rf[512 + o + 1] + rf[1024 + o + 1] + rf[1536 + o + 1];
    float* Po = P + (size_t)kchunk * (2 * 4096 * 32)
                  + (hid ? (size_t)4096 * 32 : 0)
                  + (size_t)m0 * 32 + o;
    *(f32x2*)Po = v;
}

// out[b][s][h] = sum_r seqE[b*1024+s][r]*w[r] * hidE[b*1024+h][r]
// Embeddings arrive as 4 K-chunk partials: P[4][2][4096][32]; reduce on load.
// Block: b x (32-s tile) x (64-h tile). 256 threads.
__global__ __launch_bounds__(256) void k3(const float* __restrict__ P,
                                          const float* __restrict__ cpw,
                                          float* __restrict__ out)
{
    __shared__ float s_w[32][36];   // seq tile, pre-weighted
    __shared__ float s_h[64][36];   // hid tile
    const int tid = threadIdx.x;
    const int b  = blockIdx.z;
    const int s0 = blockIdx.x * 32;
    const int h0 = blockIdx.y * 64;
    const size_t CH = (size_t)2 * 4096 * 32;   // floats per kchunk slice

    {   // stage seq tile: 32 rows x 32 r = 256 f4, one per thread; sum 4 chunks
        const int si = tid >> 3;
        const int r4 = (tid & 7) * 4;
        const float* base = P + ((size_t)(b * 1024 + s0 + si)) * 32 + r4;
        f32x4 v = *(const f32x4*)(base)
                + *(const f32x4*)(base + CH)
                + *(const f32x4*)(base + 2 * CH)
                + *(const f32x4*)(base + 3 * CH);
        f32x4 wv = *(const f32x4*)(cpw + r4);
        v *= wv;
        *(f32x4*)&s_w[si][r4] = v;
    }
    #pragma unroll
    for (int t = 0; t < 2; ++t) {   // stage hid tile: 64 x 32 = 512 f4; sum 4 chunks
        const int fi = tid + t * 256;
        const int hx = fi >> 3;
        const int r4 = (fi & 7) * 4;
        const float* base = P + (size_t)4096 * 32
                              + ((size_t)(b * 1024 + h0 + hx)) * 32 + r4;
        f32x4 v = *(const f32x4*)(base)
                + *(const f32x4*)(base + CH)
                + *(const f32x4*)(base + 2 * CH)
                + *(const f32x4*)(base + 3 * CH);
        *(f32x4*)&s_h[hx][r4] = v;
    }
    __syncthreads();

    const int hx = tid & 63;
    const int sg = tid >> 6;
    float hv[32];
    #pragma unroll
    for (int r4 = 0; r4 < 32; r4 += 4) {
        f32x4 v = *(const f32x4*)&s_h[hx][r4];
        hv[r4] = v.x; hv[r4+1] = v.y; hv[r4+2] = v.z; hv[r4+3] = v.w;
    }
    float res[8];
    #pragma unroll
    for (int si = 0; si < 8; ++si) {
        const int s = sg * 8 + si;
        float acc = 0.f;
        #pragma unroll
        for (int r4 = 0; r4 < 32; r4 += 4) {
            f32x4 v = *(const f32x4*)&s_w[s][r4];   // broadcast across lanes
            acc += v.x * hv[r4] + v.y * hv[r4+1] + v.z * hv[r4+2] + v.w * hv[r4+3];
        }
        res[si] = acc;
    }
    #pragma unroll
    for (int si = 0; si < 8; ++si) {
        const int s = s0 + sg * 8 + si;
        out[((size_t)(b * 1024 + s)) * 1024 + h0 + hx] = res[si];
    }
}

extern "C" void kernel_launch(void* const* d_in, const int* in_sizes, int n_in,
                              void* d_out, int out_size, void* d_ws, size_t ws_size,
                              hipStream_t stream) {
    const float* hs   = (const float*)d_in[0];
    // d_in[1] = all_indices: identically (n/H, n%H) -> computed implicitly
    const float* seqW = (const float*)d_in[2];
    const float* hidW = (const float*)d_in[3];
    const float* cpw  = (const float*)d_in[4];
    float* out = (float*)d_out;

    float* P = (float*)d_ws;              // [4][2][4096][32] fp32, 4 MB

    gemm_fused<<<2048, 256, 0, stream>>>(hs, seqW, hidW, P);
    dim3 grid3(32, 16, 4);
    k3<<<grid3, 256, 0, stream>>>(P, cpw, out);
}

// Round 4
// 25.221 us; speedup vs baseline: 1.1451x; 1.1451x over previous
//
#include <hip/hip_runtime.h>

typedef __attribute__((ext_vector_type(8))) short bf16x8;
typedef __attribute__((ext_vector_type(4))) float f32x4;
typedef __attribute__((ext_vector_type(2))) float f32x2;

// Native cast -> fptrunc float->bfloat -> v_cvt_pk_bf16_f32 on gfx950 (RNE).
// (m240: scalar casts beat hand-written conversion arithmetic / inline asm.)
__device__ __forceinline__ short f2bf(float x) {
    union { __bf16 h; short s; } u;
    u.h = (__bf16)x;
    return u.s;
}

// Fused skinny GEMMs, full-K per block.
//   blocks 0..255  : seqE[m][r] = sum_k hs[m*1024+k]          * seqW[r][k]   (m=b*S+s, k=h)
//   blocks 256..511: hidE[m][r] = sum_k hs[b*2^20 + k*1024+h] * hidW[r][k]   (m=b*H+h, k=s)
// 4 waves/block, wave w owns K-slice [w*256, w*256+256) of the SAME 16-row tile;
// LDS reduce across waves writes final fp32 embeddings (no partial round-trip).
// MFMA k-slot mapping kg(g,j)=8g+j used identically for A and B fragments ->
// result invariant to the HW's internal k permutation.
__global__ __launch_bounds__(256) void gemm_fused(
    const float* __restrict__ hs, const float* __restrict__ seqW,
    const float* __restrict__ hidW, float* __restrict__ E /* [2][4096][32] */)
{
    __shared__ float red[4][16][32];

    const int bid = blockIdx.x;
    const bool hid = bid >= 256;
    const int mt  = hid ? bid - 256 : bid;
    const int tid = threadIdx.x;
    const int wv  = tid >> 6;
    const int l   = tid & 63;
    const int l15 = l & 15;
    const int g   = l >> 4;
    const int m0  = mt * 16;
    const int mrow = m0 + l15;

    const float* __restrict__ W = hid ? hidW : seqW;
    size_t arow;
    if (hid) arow = ((size_t)(mrow >> 10) << 20) + (size_t)(mrow & 1023);
    else     arow = (size_t)mrow << 10;

    f32x4 acc0 = {0.f,0.f,0.f,0.f}, acc1 = {0.f,0.f,0.f,0.f};
    const int kbase = wv * 256;

    for (int ks = 0; ks < 8; ++ks) {
        const int kb = kbase + ks * 32 + g * 8;
        bf16x8 af, bf0, bf1;
        if (hid) {
            const float* pa = hs + arow + (size_t)kb * 1024;
            float a[8];
            #pragma unroll
            for (int j = 0; j < 8; ++j) a[j] = pa[(size_t)j * 1024];
            #pragma unroll
            for (int j = 0; j < 8; ++j) af[j] = f2bf(a[j]);
        } else {
            const f32x4* pa = (const f32x4*)(hs + arow + kb);
            f32x4 a0 = pa[0], a1 = pa[1];
            af[0]=f2bf(a0.x); af[1]=f2bf(a0.y); af[2]=f2bf(a0.z); af[3]=f2bf(a0.w);
            af[4]=f2bf(a1.x); af[5]=f2bf(a1.y); af[6]=f2bf(a1.z); af[7]=f2bf(a1.w);
        }
        {
            const f32x4* pb = (const f32x4*)(W + (size_t)l15 * 1024 + kb);
            f32x4 b0 = pb[0], b1 = pb[1];
            bf0[0]=f2bf(b0.x); bf0[1]=f2bf(b0.y); bf0[2]=f2bf(b0.z); bf0[3]=f2bf(b0.w);
            bf0[4]=f2bf(b1.x); bf0[5]=f2bf(b1.y); bf0[6]=f2bf(b1.z); bf0[7]=f2bf(b1.w);
        }
        {
            const f32x4* pb = (const f32x4*)(W + (size_t)(l15 + 16) * 1024 + kb);
            f32x4 b0 = pb[0], b1 = pb[1];
            bf1[0]=f2bf(b0.x); bf1[1]=f2bf(b0.y); bf1[2]=f2bf(b0.z); bf1[3]=f2bf(b0.w);
            bf1[4]=f2bf(b1.x); bf1[5]=f2bf(b1.y); bf1[6]=f2bf(b1.z); bf1[7]=f2bf(b1.w);
        }
        acc0 = __builtin_amdgcn_mfma_f32_16x16x32_bf16(af, bf0, acc0, 0, 0, 0);
        acc1 = __builtin_amdgcn_mfma_f32_16x16x32_bf16(af, bf1, acc1, 0, 0, 0);
    }

    // C/D layout (m89-verified): col = lane&15, row = (lane>>4)*4 + reg
    #pragma unroll
    for (int r = 0; r < 4; ++r) {
        red[wv][4 * g + r][l15]      = acc0[r];
        red[wv][4 * g + r][l15 + 16] = acc1[r];
    }
    __syncthreads();

    // Sum 4 wave-partials; each thread produces 2 consecutive outputs (f32x2 store).
    const int o = tid * 2;
    const float* rf = &red[0][0][0];
    f32x2 v;
    v.x = rf[o]     + rf[512 + o]     + rf[1024 + o]     + rf[1536 + o];
    v.y = rf[o + 1] + rf[512 + o + 1] + rf[1024 + o + 1] + rf[1536 + o + 1];
    float* Eo = E + (hid ? (size_t)4096 * 32 : 0) + (size_t)m0 * 32 + o;
    *(f32x2*)Eo = v;
}

// out[b][s][h] = sum_r seqE[b*1024+s][r]*w[r] * hidE[b*1024+h][r]
// Block: b x (32-s tile) x (64-h tile). 256 threads.
__global__ __launch_bounds__(256) void k3(const float* __restrict__ SeqE,
                                          const float* __restrict__ HidE,
                                          const float* __restrict__ cpw,
                                          float* __restrict__ out)
{
    __shared__ float s_w[32][36];   // seq tile, pre-weighted
    __shared__ float s_h[64][36];   // hid tile
    const int tid = threadIdx.x;
    const int b  = blockIdx.z;
    const int s0 = blockIdx.x * 32;
    const int h0 = blockIdx.y * 64;

    {   // stage seq tile: 32 rows x 32 r = 256 f4, one per thread
        const int si = tid >> 3;
        const int r4 = (tid & 7) * 4;
        f32x4 v  = *(const f32x4*)(SeqE + ((size_t)(b * 1024 + s0 + si)) * 32 + r4);
        f32x4 wv = *(const f32x4*)(cpw + r4);
        v *= wv;
        *(f32x4*)&s_w[si][r4] = v;
    }
    #pragma unroll
    for (int t = 0; t < 2; ++t) {   // stage hid tile: 64 x 32 = 512 f4
        const int fi = tid + t * 256;
        const int hx = fi >> 3;
        const int r4 = (fi & 7) * 4;
        f32x4 v = *(const f32x4*)(HidE + ((size_t)(b * 1024 + h0 + hx)) * 32 + r4);
        *(f32x4*)&s_h[hx][r4] = v;
    }
    __syncthreads();

    const int hx = tid & 63;
    const int sg = tid >> 6;
    float hv[32];
    #pragma unroll
    for (int r4 = 0; r4 < 32; r4 += 4) {
        f32x4 v = *(const f32x4*)&s_h[hx][r4];
        hv[r4] = v.x; hv[r4+1] = v.y; hv[r4+2] = v.z; hv[r4+3] = v.w;
    }
    float res[8];
    #pragma unroll
    for (int si = 0; si < 8; ++si) {
        const int s = sg * 8 + si;
        float acc = 0.f;
        #pragma unroll
        for (int r4 = 0; r4 < 32; r4 += 4) {
            f32x4 v = *(const f32x4*)&s_w[s][r4];   // broadcast across lanes
            acc += v.x * hv[r4] + v.y * hv[r4+1] + v.z * hv[r4+2] + v.w * hv[r4+3];
        }
        res[si] = acc;
    }
    #pragma unroll
    for (int si = 0; si < 8; ++si) {
        const int s = s0 + sg * 8 + si;
        out[((size_t)(b * 1024 + s)) * 1024 + h0 + hx] = res[si];
    }
}

extern "C" void kernel_launch(void* const* d_in, const int* in_sizes, int n_in,
                              void* d_out, int out_size, void* d_ws, size_t ws_size,
                              hipStream_t stream) {
    const float* hs   = (const float*)d_in[0];
    // d_in[1] = all_indices: identically (n/H, n%H) -> computed implicitly
    const float* seqW = (const float*)d_in[2];
    const float* hidW = (const float*)d_in[3];
    const float* cpw  = (const float*)d_in[4];
    float* out = (float*)d_out;

    float* E = (float*)d_ws;              // [2][4096][32] fp32, 1 MB

    gemm_fused<<<512, 256, 0, stream>>>(hs, seqW, hidW, E);
    dim3 grid3(32, 16, 4);
    k3<<<grid3, 256, 0, stream>>>(E, E + (size_t)4096 * 32, cpw, out);
}